// Round 2
// baseline (52.353 us; speedup 1.0000x reference)
//
#include <hip/hip_runtime.h>

#define NBATCH 8
#define HH 256
#define WW 256
#define CC 64
#define HWPTS 65536   // HH*WW
#define NSTEPS_ 50

// ---------------------------------------------------------------------------
// Kernel 1: build per-(b,t) affine matrices A (2x3) from theta.
// Tessellation: NX=2, NY=4; 15 corners (idx j*3+i), 8 centers (idx 15+j*2+i).
// Free verts: corner(1,1)=4 ->slot0, (1,2)=7 ->slot1, (1,3)=10 ->slot2,
//             centers 15..22 -> slots 3..10.  THETA_DIM = 22.
// Output layout (transposed for conflict-free LDS reads):
//   Aout[b*192 + w*32 + t],  w = 0..5  (a00,a01,a02,a10,a11,a12)
// ---------------------------------------------------------------------------
__global__ __launch_bounds__(256) void cpab_build_A(const float* __restrict__ theta,
                                                    float* __restrict__ Aout) {
  int tid = threadIdx.x;           // 0..255 == b*32 + t
  int b = tid >> 5, t = tid & 31;
  int cell = t >> 2, k = t & 3;
  int ci = cell & 1, cj = cell >> 1;
  int ll = cj * 3 + ci;
  int lr = ll + 1, ul = ll + 3, ur = ll + 4;
  int cen = 15 + cj * 2 + ci;
  int v0, v1, v2 = cen;
  if (k == 0)      { v0 = ll; v1 = lr; }
  else if (k == 1) { v0 = lr; v1 = ur; }
  else if (k == 2) { v0 = ur; v1 = ul; }
  else             { v0 = ul; v1 = ll; }

  int vs[3] = {v0, v1, v2};
  double xs[3], ys[3];
  float Vx[3], Vy[3];
  for (int q = 0; q < 3; ++q) {
    int v = vs[q];
    if (v < 15) { xs[q] = (double)(v % 3) * 0.5; ys[q] = (double)(v / 3) * 0.25; }
    else { int u = v - 15; xs[q] = ((double)(u & 1) + 0.5) * 0.5;
           ys[q] = ((double)(u >> 1) + 0.5) * 0.25; }
    int s = (v == 4) ? 0 : (v == 7) ? 1 : (v == 10) ? 2 : (v >= 15) ? (v - 12) : -1;
    if (s >= 0) { Vx[q] = theta[b * 22 + 2 * s]; Vy[q] = theta[b * 22 + 2 * s + 1]; }
    else        { Vx[q] = 0.f; Vy[q] = 0.f; }
  }
  double x0 = xs[0], x1 = xs[1], x2 = xs[2];
  double y0 = ys[0], y1 = ys[1], y2 = ys[2];
  double det = x0 * (y1 - y2) - x1 * (y0 - y2) + x2 * (y0 - y1);
  // P = [[x0,x1,x2],[y0,y1,y2],[1,1,1]];  inv[v][w] = (P^{-1})[v][w] = adj^T/det
  double inv[3][3] = {
      {y1 - y2, x2 - x1, x1 * y2 - x2 * y1},
      {y2 - y0, x0 - x2, x2 * y0 - x0 * y2},
      {y0 - y1, x1 - x0, x0 * y1 - x1 * y0}};
  for (int w = 0; w < 3; ++w) {
    float i0 = (float)(inv[0][w] / det);
    float i1 = (float)(inv[1][w] / det);
    float i2 = (float)(inv[2][w] / det);
    // A[c][w] = sum_v V[v][c] * invP[v][w]   (f32, left-to-right like einsum)
    float ax = __fadd_rn(__fadd_rn(__fmul_rn(Vx[0], i0), __fmul_rn(Vx[1], i1)),
                         __fmul_rn(Vx[2], i2));
    float ay = __fadd_rn(__fadd_rn(__fmul_rn(Vy[0], i0), __fmul_rn(Vy[1], i1)),
                         __fmul_rn(Vy[2], i2));
    Aout[b * 192 + w * 32 + t]       = ax;
    Aout[b * 192 + (w + 3) * 32 + t] = ay;
  }
}

// ---------------------------------------------------------------------------
// Kernel 2: per block: 256 grid points. Phase 1: all 256 threads integrate
// their own point (50 Euler steps, A in LDS, conflict-free transposed layout).
// Phase 2: 256 pts x 16 float4 chunks = 4096 tasks, 16 per thread; 16
// consecutive lanes share a point -> LDS broadcast + coalesced 256B segments.
// ---------------------------------------------------------------------------
__global__ __launch_bounds__(256) void cpab_warp_sample(const float* __restrict__ xin,
                                                        const float* __restrict__ Ain,
                                                        float* __restrict__ out) {
  __shared__ float sA[192];
  __shared__ int   sX0[256], sY0[256];
  __shared__ float sWx[256], sWy[256];

  int tid = threadIdx.x;
  int base_pt = blockIdx.x << 8;          // 256 points per block
  int b = blockIdx.x >> 8;                // 256 blocks per batch (never straddles)

  if (tid < 192) sA[tid] = Ain[b * 192 + tid];
  __syncthreads();

  {
    int hw = (base_pt + tid) & (HWPTS - 1);
    int w = hw & 255, h = hw >> 8;
    // np.linspace(0,1,256): i * (1/255) with exact endpoint
    float px = (w == 255) ? 1.0f : __fmul_rn((float)w, 1.0f / 255.0f);
    float py = (h == 255) ? 1.0f : __fmul_rn((float)h, 1.0f / 255.0f);
#pragma unroll 1
    for (int s = 0; s < NSTEPS_; ++s) {
      float xc = fminf(fmaxf(px, 0.f), 1.f) * 2.0f;   // exact (*2)
      float yc = fminf(fmaxf(py, 0.f), 1.f) * 4.0f;   // exact (*4)
      float cxf = fminf(floorf(xc), 1.0f);
      float cyf = fminf(floorf(yc), 3.0f);
      float xr = xc - cxf, yr = yc - cyf;
      int tri = (yr <= xr) ? ((yr <= 1.0f - xr) ? 0 : 1)
                           : ((yr <= 1.0f - xr) ? 3 : 2);
      int cid = ((((int)cyf) << 1) + (int)cxf) * 4 + tri;
      float a0 = sA[cid],       a1 = sA[32 + cid],  a2 = sA[64 + cid];
      float a3 = sA[96 + cid],  a4 = sA[128 + cid], a5 = sA[160 + cid];
      // v = (a0*px + a1*py) + a2  -- no fma, mimic numpy rounding
      float vx = __fadd_rn(__fadd_rn(__fmul_rn(a0, px), __fmul_rn(a1, py)), a2);
      float vy = __fadd_rn(__fadd_rn(__fmul_rn(a3, px), __fmul_rn(a4, py)), a5);
      px = __fadd_rn(px, __fmul_rn(0.02f, vx));
      py = __fadd_rn(py, __fmul_rn(0.02f, vy));
    }
    float gx = __fmul_rn(fminf(fmaxf(px, 0.f), 1.f), 255.0f);
    float gy = __fmul_rn(fminf(fmaxf(py, 0.f), 1.f), 255.0f);
    int ix = min((int)gx, 254);   // gx >= 0 so (int) == floor
    int iy = min((int)gy, 254);
    sX0[tid] = ix; sY0[tid] = iy;
    sWx[tid] = __fadd_rn(gx, -(float)ix);
    sWy[tid] = __fadd_rn(gy, -(float)iy);
  }
  __syncthreads();

  const float* xb = xin + (size_t)b * ((size_t)HWPTS * CC);
  float* ob = out + (size_t)base_pt * CC;
#pragma unroll
  for (int r = 0; r < 16; ++r) {
    int task = (r << 8) + tid;
    int pi = task >> 4;
    int ch = (task & 15) << 2;
    int ix = sX0[pi], iy = sY0[pi];
    float wx = sWx[pi], wy = sWy[pi];
    const float4* p00 = (const float4*)(xb + (size_t)((iy << 8) + ix) * CC + ch);
    float4 v00 = p00[0];
    float4 v01 = p00[16];              // x0+1
    float4 v10 = p00[16 * 256];        // y0+1
    float4 v11 = p00[16 * 256 + 16];
    float w00 = (1.f - wx) * (1.f - wy);
    float w01 = wx * (1.f - wy);
    float w10 = (1.f - wx) * wy;
    float w11 = wx * wy;
    float4 o;
    o.x = v00.x * w00 + v01.x * w01 + v10.x * w10 + v11.x * w11;
    o.y = v00.y * w00 + v01.y * w01 + v10.y * w10 + v11.y * w11;
    o.z = v00.z * w00 + v01.z * w01 + v10.z * w10 + v11.z * w11;
    o.w = v00.w * w00 + v01.w * w01 + v10.w * w10 + v11.w * w11;
    *(float4*)(ob + (size_t)pi * CC + ch) = o;
  }
}

extern "C" void kernel_launch(void* const* d_in, const int* in_sizes, int n_in,
                              void* d_out, int out_size, void* d_ws, size_t ws_size,
                              hipStream_t stream) {
  const float* x     = (const float*)d_in[0];   // (8,256,256,64) f32
  const float* theta = (const float*)d_in[1];   // (8,22) f32
  float* out  = (float*)d_out;                  // (8,256,256,64) f32
  float* Abuf = (float*)d_ws;                   // 8*192 floats = 6 KiB

  cpab_build_A<<<1, 256, 0, stream>>>(theta, Abuf);
  cpab_warp_sample<<<NBATCH * HWPTS / 256, 256, 0, stream>>>(x, Abuf, out);
}

// Round 3
// 45.071 us; speedup vs baseline: 1.1616x; 1.1616x over previous
//
#include <hip/hip_runtime.h>

#define NBATCH 8
#define HH 256
#define WW 256
#define CC 64
#define HWPTS 65536   // HH*WW
#define NSTEPS_ 50

typedef float vf4 __attribute__((ext_vector_type(4)));

// ---------------------------------------------------------------------------
// Kernel 1: build per-(b,t) affine matrices A (2x3) from theta.
// Output layout (float2-packed, transposed for conflict-free LDS b64 reads):
//   Aout[b*192 + (w*32 + t)*2 + c],  w = 0..2 (x,y,1 coeff), c = 0:vx 1:vy
// ---------------------------------------------------------------------------
__global__ __launch_bounds__(256) void cpab_build_A(const float* __restrict__ theta,
                                                    float* __restrict__ Aout) {
  int tid = threadIdx.x;           // 0..255 == b*32 + t
  int b = tid >> 5, t = tid & 31;
  int cell = t >> 2, k = t & 3;
  int ci = cell & 1, cj = cell >> 1;
  int ll = cj * 3 + ci;
  int lr = ll + 1, ul = ll + 3, ur = ll + 4;
  int cen = 15 + cj * 2 + ci;
  int v0, v1, v2 = cen;
  if (k == 0)      { v0 = ll; v1 = lr; }
  else if (k == 1) { v0 = lr; v1 = ur; }
  else if (k == 2) { v0 = ur; v1 = ul; }
  else             { v0 = ul; v1 = ll; }

  int vs[3] = {v0, v1, v2};
  double xs[3], ys[3];
  float Vx[3], Vy[3];
  for (int q = 0; q < 3; ++q) {
    int v = vs[q];
    if (v < 15) { xs[q] = (double)(v % 3) * 0.5; ys[q] = (double)(v / 3) * 0.25; }
    else { int u = v - 15; xs[q] = ((double)(u & 1) + 0.5) * 0.5;
           ys[q] = ((double)(u >> 1) + 0.5) * 0.25; }
    int s = (v == 4) ? 0 : (v == 7) ? 1 : (v == 10) ? 2 : (v >= 15) ? (v - 12) : -1;
    if (s >= 0) { Vx[q] = theta[b * 22 + 2 * s]; Vy[q] = theta[b * 22 + 2 * s + 1]; }
    else        { Vx[q] = 0.f; Vy[q] = 0.f; }
  }
  double x0 = xs[0], x1 = xs[1], x2 = xs[2];
  double y0 = ys[0], y1 = ys[1], y2 = ys[2];
  double det = x0 * (y1 - y2) - x1 * (y0 - y2) + x2 * (y0 - y1);
  // P = [[x0,x1,x2],[y0,y1,y2],[1,1,1]];  inv = adj^T / det
  double inv[3][3] = {
      {y1 - y2, x2 - x1, x1 * y2 - x2 * y1},
      {y2 - y0, x0 - x2, x2 * y0 - x0 * y2},
      {y0 - y1, x1 - x0, x0 * y1 - x1 * y0}};
  for (int w = 0; w < 3; ++w) {
    float i0 = (float)(inv[0][w] / det);
    float i1 = (float)(inv[1][w] / det);
    float i2 = (float)(inv[2][w] / det);
    float ax = __fadd_rn(__fadd_rn(__fmul_rn(Vx[0], i0), __fmul_rn(Vx[1], i1)),
                         __fmul_rn(Vx[2], i2));
    float ay = __fadd_rn(__fadd_rn(__fmul_rn(Vy[0], i0), __fmul_rn(Vy[1], i1)),
                         __fmul_rn(Vy[2], i2));
    Aout[b * 192 + (w * 32 + t) * 2]     = ax;
    Aout[b * 192 + (w * 32 + t) * 2 + 1] = ay;
  }
}

// ---------------------------------------------------------------------------
// Kernel 2 (fused): phase 1 integrates 256 points/block (A float2-packed in
// LDS, 3x ds_read_b64/step); phase 2 gathers+blends 64 channels/point with
// 2-task grouping (8 float4 loads in flight) and nontemporal stores.
// Block swizzle: XCD k <- all 256 rows of batch k (L2 row-overlap reuse).
// ---------------------------------------------------------------------------
__global__ __launch_bounds__(256) void cpab_warp_sample(const float* __restrict__ xin,
                                                        const float* __restrict__ Ain,
                                                        float* __restrict__ out) {
  __shared__ float2 sA2[96];
  __shared__ int   sX0[256], sY0[256];
  __shared__ float sWx[256], sWy[256];

  int tid = threadIdx.x;
  int bid = blockIdx.x;
  int swz = ((bid & 7) << 8) | (bid >> 3);   // bijective: 2048 = 8 * 256
  int base_pt = swz << 8;                    // 256 points per block
  int b = swz >> 8;                          // = bid & 7 (batch == XCD)

  if (tid < 192) ((float*)sA2)[tid] = Ain[b * 192 + tid];
  __syncthreads();

  {
    int hw = (base_pt + tid) & (HWPTS - 1);
    int w = hw & 255, h = hw >> 8;
    // np.linspace(0,1,256): i * (1/255) with exact endpoint
    float px = (w == 255) ? 1.0f : __fmul_rn((float)w, 1.0f / 255.0f);
    float py = (h == 255) ? 1.0f : __fmul_rn((float)h, 1.0f / 255.0f);
#pragma unroll 1
    for (int s = 0; s < NSTEPS_; ++s) {
      float xc = fminf(fmaxf(px, 0.f), 1.f) * 2.0f;   // exact (*2)
      float yc = fminf(fmaxf(py, 0.f), 1.f) * 4.0f;   // exact (*4)
      float cxf = fminf(floorf(xc), 1.0f);
      float cyf = fminf(floorf(yc), 3.0f);
      float xr = xc - cxf, yr = yc - cyf;
      int tri = (yr <= xr) ? ((yr <= 1.0f - xr) ? 0 : 1)
                           : ((yr <= 1.0f - xr) ? 3 : 2);
      int cid = ((((int)cyf) << 1) + (int)cxf) * 4 + tri;
      float2 q0 = sA2[cid];        // {a00, a10}
      float2 q1 = sA2[32 + cid];   // {a01, a11}
      float2 q2 = sA2[64 + cid];   // {a02, a12}
      float vx = __fadd_rn(__fadd_rn(__fmul_rn(q0.x, px), __fmul_rn(q1.x, py)), q2.x);
      float vy = __fadd_rn(__fadd_rn(__fmul_rn(q0.y, px), __fmul_rn(q1.y, py)), q2.y);
      px = __fadd_rn(px, __fmul_rn(0.02f, vx));
      py = __fadd_rn(py, __fmul_rn(0.02f, vy));
    }
    float gx = __fmul_rn(fminf(fmaxf(px, 0.f), 1.f), 255.0f);
    float gy = __fmul_rn(fminf(fmaxf(py, 0.f), 1.f), 255.0f);
    int ix = min((int)gx, 254);   // gx >= 0 so (int) == floor
    int iy = min((int)gy, 254);
    sX0[tid] = ix; sY0[tid] = iy;
    sWx[tid] = __fadd_rn(gx, -(float)ix);
    sWy[tid] = __fadd_rn(gy, -(float)iy);
  }
  __syncthreads();

  const float* xb = xin + (size_t)b * ((size_t)HWPTS * CC);
  float* ob = out + (size_t)base_pt * CC;
#pragma unroll
  for (int r = 0; r < 8; ++r) {
    int t0 = (r << 8) + tid;       // tasks 0..2047
    int p0 = t0 >> 4;              // point 0..127
    int c0 = (t0 & 15) << 2;       // channel chunk
    int p1 = p0 + 128;             // paired task t0 + 2048

    int ix0 = sX0[p0], iy0 = sY0[p0];
    float wx0 = sWx[p0], wy0 = sWy[p0];
    int ix1 = sX0[p1], iy1 = sY0[p1];
    float wx1 = sWx[p1], wy1 = sWy[p1];

    const float4* q0 = (const float4*)(xb + (size_t)((iy0 << 8) + ix0) * CC + c0);
    const float4* q1 = (const float4*)(xb + (size_t)((iy1 << 8) + ix1) * CC + c0);
    float4 a00 = q0[0];
    float4 a01 = q0[16];            // x0+1
    float4 a10 = q0[16 * 256];      // y0+1
    float4 a11 = q0[16 * 256 + 16];
    float4 b00 = q1[0];
    float4 b01 = q1[16];
    float4 b10 = q1[16 * 256];
    float4 b11 = q1[16 * 256 + 16];

    float aw00 = (1.f - wx0) * (1.f - wy0);
    float aw01 = wx0 * (1.f - wy0);
    float aw10 = (1.f - wx0) * wy0;
    float aw11 = wx0 * wy0;
    float bw00 = (1.f - wx1) * (1.f - wy1);
    float bw01 = wx1 * (1.f - wy1);
    float bw10 = (1.f - wx1) * wy1;
    float bw11 = wx1 * wy1;

    vf4 o0, o1;
    o0.x = a00.x * aw00 + a01.x * aw01 + a10.x * aw10 + a11.x * aw11;
    o0.y = a00.y * aw00 + a01.y * aw01 + a10.y * aw10 + a11.y * aw11;
    o0.z = a00.z * aw00 + a01.z * aw01 + a10.z * aw10 + a11.z * aw11;
    o0.w = a00.w * aw00 + a01.w * aw01 + a10.w * aw10 + a11.w * aw11;
    o1.x = b00.x * bw00 + b01.x * bw01 + b10.x * bw10 + b11.x * bw11;
    o1.y = b00.y * bw00 + b01.y * bw01 + b10.y * bw10 + b11.y * bw11;
    o1.z = b00.z * bw00 + b01.z * bw01 + b10.z * bw10 + b11.z * bw11;
    o1.w = b00.w * bw00 + b01.w * bw01 + b10.w * bw10 + b11.w * bw11;

    __builtin_nontemporal_store(o0, (vf4*)(ob + (size_t)p0 * CC + c0));
    __builtin_nontemporal_store(o1, (vf4*)(ob + (size_t)p1 * CC + c0));
  }
}

extern "C" void kernel_launch(void* const* d_in, const int* in_sizes, int n_in,
                              void* d_out, int out_size, void* d_ws, size_t ws_size,
                              hipStream_t stream) {
  const float* x     = (const float*)d_in[0];   // (8,256,256,64) f32
  const float* theta = (const float*)d_in[1];   // (8,22) f32
  float* out  = (float*)d_out;                  // (8,256,256,64) f32
  float* Abuf = (float*)d_ws;                   // 8*192 floats = 6 KiB

  cpab_build_A<<<1, 256, 0, stream>>>(theta, Abuf);
  cpab_warp_sample<<<NBATCH * HWPTS / 256, 256, 0, stream>>>(x, Abuf, out);
}